// Round 9
// baseline (142.532 us; speedup 1.0000x reference)
//
#include <hip/hip_runtime.h>

#define N_TOK 4096
#define C_DIM 256
#define HEADS 8
#define HDIM  32
#define KSPLIT 4
#define QSCALE 0.17677669529663687f
#define L2E    1.4426950408889634f

typedef __attribute__((ext_vector_type(8))) short bf16x8;
typedef __attribute__((ext_vector_type(4))) float f32x4;
typedef __attribute__((ext_vector_type(4))) unsigned int u32x4;
typedef __attribute__((ext_vector_type(8))) unsigned short u16x8;

static __device__ __forceinline__ unsigned short f2bf(float f) {
  union { float f; unsigned int u; } c; c.f = f;
  return (unsigned short)((c.u + 0x8000u) >> 16);
}
static __device__ __forceinline__ float bf2f(unsigned short u) {
  union { unsigned int i; float f; } c; c.i = ((unsigned int)u) << 16;
  return c.f;
}
static __device__ __forceinline__ float fexp2(float x) {
  float r; asm("v_exp_f32 %0, %1" : "=v"(r) : "v"(x)); return r;
}
static __device__ __forceinline__ unsigned int cvt_pk(float lo, float hi) {
  unsigned int r; asm("v_cvt_pk_bf16_f32 %0, %1, %2" : "=v"(r) : "v"(lo), "v"(hi)); return r;
}

// ---------------------------------------------------------------------------
// Kernel 0: split W = [wq*QSCALE*L2E; wk; wv; wo] (1024x256 fp32) -> hi/lo bf16
// ---------------------------------------------------------------------------
__global__ __launch_bounds__(256) void wsplit(
    const float* __restrict__ wq, const float* __restrict__ wk,
    const float* __restrict__ wv, const float* __restrict__ wo,
    unsigned short* __restrict__ Whi, unsigned short* __restrict__ Wlo)
{
  const int i4  = blockIdx.x * 256 + threadIdx.x;
  const int idx = i4 * 4;
  const int r   = idx >> 8;
  const float* src; int off; float scl = 1.f;
  if (r < 256)      { src = wq; off = idx;          scl = QSCALE * L2E; }
  else if (r < 512) { src = wk; off = idx - 65536;  }
  else if (r < 768) { src = wv; off = idx - 131072; }
  else              { src = wo; off = idx - 196608; }
  float4 v = *reinterpret_cast<const float4*>(&src[off]);
  v.x *= scl; v.y *= scl; v.z *= scl; v.w *= scl;
  ushort4 h, l;
  h.x = f2bf(v.x); l.x = f2bf(v.x - bf2f(h.x));
  h.y = f2bf(v.y); l.y = f2bf(v.y - bf2f(h.y));
  h.z = f2bf(v.z); l.z = f2bf(v.z - bf2f(h.z));
  h.w = f2bf(v.w); l.w = f2bf(v.w - bf2f(h.w));
  *reinterpret_cast<ushort4*>(&Whi[idx]) = h;
  *reinterpret_cast<ushort4*>(&Wlo[idx]) = l;
}

// ---------------------------------------------------------------------------
// Kernel 0b: transpose+split fp32 [256][4096] -> hi/lo bf16 [4096][256] (x)
// ---------------------------------------------------------------------------
__global__ __launch_bounds__(256) void tsplit(
    const float* __restrict__ src,
    unsigned short* __restrict__ dhi, unsigned short* __restrict__ dlo)
{
  __shared__ float T[64][69];
  const int c0 = blockIdx.y * 64, n0 = blockIdx.x * 64;
  const int t = threadIdx.x;
  {
    const int cl = t >> 2, ng = (t & 3) * 16;
    #pragma unroll
    for (int jj = 0; jj < 4; jj++) {
      const float4 v = *reinterpret_cast<const float4*>(&src[(c0 + cl) * N_TOK + n0 + ng + jj * 4]);
      T[cl][ng + jj * 4 + 0] = v.x; T[cl][ng + jj * 4 + 1] = v.y;
      T[cl][ng + jj * 4 + 2] = v.z; T[cl][ng + jj * 4 + 3] = v.w;
    }
  }
  __syncthreads();
  {
    const int nl = t >> 2, cg = (t & 3) * 16;
    u16x8 h0, h1, l0, l1;
    #pragma unroll
    for (int j = 0; j < 8; j++) {
      const float v = T[cg + j][nl];
      h0[j] = f2bf(v); l0[j] = f2bf(v - bf2f(h0[j]));
    }
    #pragma unroll
    for (int j = 0; j < 8; j++) {
      const float v = T[cg + 8 + j][nl];
      h1[j] = f2bf(v); l1[j] = f2bf(v - bf2f(h1[j]));
    }
    const size_t base = (size_t)(n0 + nl) * C_DIM + c0 + cg;
    *reinterpret_cast<u16x8*>(&dhi[base])     = h0;
    *reinterpret_cast<u16x8*>(&dhi[base + 8]) = h1;
    *reinterpret_cast<u16x8*>(&dlo[base])     = l0;
    *reinterpret_cast<u16x8*>(&dlo[base + 8]) = l1;
  }
}

// ---------------------------------------------------------------------------
// Kernel 1: QKV projection (R7-proven: split-bf16, 3 MFMA, BK=32 phases).
// B tile staged in fragment-read order; K rows written transposed to Kt.
// ---------------------------------------------------------------------------
__global__ __launch_bounds__(256) void qkv_mfma(
    const unsigned short* __restrict__ Whi, const unsigned short* __restrict__ Wlo,
    const unsigned short* __restrict__ Xhi, const unsigned short* __restrict__ Xlo,
    unsigned short* __restrict__ Qkv, unsigned short* __restrict__ Kt)
{
  const int n0 = blockIdx.x * 64;
  const int by = blockIdx.y;                 // 0..11
  const int tid = threadIdx.x;
  const int w = tid >> 6, lane = tid & 63, lq = lane & 15, g = lane >> 4;
  const int o0 = by * 64 + w * 16;

  __shared__ unsigned short Bs[2][4096];     // 8KB per buffer

  const int e0l = tid & 63, e0f = tid >> 6;
  const unsigned short* s0p; const unsigned short* s1p;
  {
    const int lq_ = e0l & 15, g_ = e0l >> 4;
    const int f0 = e0f, f1 = e0f + 4;
    s0p = ((f0 & 1) ? Xlo : Xhi) + (size_t)(n0 + (f0 >> 1) * 16 + lq_) * C_DIM + 8 * g_;
    s1p = ((f1 & 1) ? Xlo : Xhi) + (size_t)(n0 + (f1 >> 1) * 16 + lq_) * C_DIM + 8 * g_;
  }
  const unsigned short* ahp = &Whi[(size_t)(o0 + lq) * C_DIM + 8 * g];
  const unsigned short* alp = &Wlo[(size_t)(o0 + lq) * C_DIM + 8 * g];

  f32x4 acc[4] = {{0.f,0.f,0.f,0.f},{0.f,0.f,0.f,0.f},{0.f,0.f,0.f,0.f},{0.f,0.f,0.f,0.f}};

  bf16x8 ah = *reinterpret_cast<const bf16x8*>(ahp);
  bf16x8 al = *reinterpret_cast<const bf16x8*>(alp);
  {
    const bf16x8 b0 = *reinterpret_cast<const bf16x8*>(s0p);
    const bf16x8 b1 = *reinterpret_cast<const bf16x8*>(s1p);
    *reinterpret_cast<bf16x8*>(&Bs[0][(size_t)tid * 8]) = b0;
    *reinterpret_cast<bf16x8*>(&Bs[0][((size_t)tid + 256) * 8]) = b1;
  }
  __syncthreads();

  int cur = 0;
  #pragma unroll
  for (int kk = 0; kk < 8; kk++) {
    bf16x8 nb0 = {}, nb1 = {}, nah = {}, nal = {};
    if (kk < 7) {
      const int ko = (kk + 1) * 32;
      nb0 = *reinterpret_cast<const bf16x8*>(s0p + ko);
      nb1 = *reinterpret_cast<const bf16x8*>(s1p + ko);
      nah = *reinterpret_cast<const bf16x8*>(ahp + ko);
      nal = *reinterpret_cast<const bf16x8*>(alp + ko);
    }
    #pragma unroll
    for (int ns = 0; ns < 4; ns++) {
      const bf16x8 bh = *reinterpret_cast<const bf16x8*>(&Bs[cur][(size_t)((ns * 2 + 0) * 64 + lane) * 8]);
      const bf16x8 bl = *reinterpret_cast<const bf16x8*>(&Bs[cur][(size_t)((ns * 2 + 1) * 64 + lane) * 8]);
      acc[ns] = __builtin_amdgcn_mfma_f32_16x16x32_bf16(ah, bh, acc[ns], 0, 0, 0);
      acc[ns] = __builtin_amdgcn_mfma_f32_16x16x32_bf16(ah, bl, acc[ns], 0, 0, 0);
      acc[ns] = __builtin_amdgcn_mfma_f32_16x16x32_bf16(al, bh, acc[ns], 0, 0, 0);
    }
    if (kk < 7) {
      *reinterpret_cast<bf16x8*>(&Bs[cur ^ 1][(size_t)tid * 8]) = nb0;
      *reinterpret_cast<bf16x8*>(&Bs[cur ^ 1][((size_t)tid + 256) * 8]) = nb1;
      ah = nah; al = nal;
    }
    __syncthreads();
    cur ^= 1;
  }

  if (by < 4 || by >= 8) {
    const int orow0 = (by < 4 ? by * 64 : (by - 8) * 64 + 512) + w * 16 + 4 * g;
    #pragma unroll
    for (int ns = 0; ns < 4; ns++)
      #pragma unroll
      for (int r = 0; r < 4; r++)
        Qkv[(size_t)(orow0 + r) * N_TOK + n0 + ns * 16 + lq] = f2bf(acc[ns][r]);
  } else {
    const int ok0 = (by - 4) * 64 + w * 16 + 4 * g;
    const int hh = ok0 >> 5, d0 = ok0 & 31;
    #pragma unroll
    for (int ns = 0; ns < 4; ns++) {
      ushort4 u;
      u.x = f2bf(acc[ns][0]); u.y = f2bf(acc[ns][1]);
      u.z = f2bf(acc[ns][2]); u.w = f2bf(acc[ns][3]);
      *reinterpret_cast<ushort4*>(&Kt[((size_t)hh * N_TOK + n0 + ns * 16 + lq) * HDIM + d0]) = u;
    }
  }
}

// ---------------------------------------------------------------------------
// Kernel 2: depthwise 3x3 conv, pad=1, initializes d_out
// ---------------------------------------------------------------------------
__global__ __launch_bounds__(256) void dwconv_kernel(
    const float* __restrict__ x, const float* __restrict__ wl,
    float* __restrict__ out)
{
  const int idx = blockIdx.x * 256 + threadIdx.x;
  const int c  = idx >> 12;
  const int yy = (idx >> 6) & 63;
  const int xx = idx & 63;
  const float* xc = x + c * 4096;
  const float* wc = wl + c * 9;
  float acc = 0.f;
  #pragma unroll
  for (int dy = 0; dy < 3; dy++) {
    const int y = yy + dy - 1;
    if (y < 0 || y > 63) continue;
    #pragma unroll
    for (int dx = 0; dx < 3; dx++) {
      const int x2 = xx + dx - 1;
      if (x2 < 0 || x2 > 63) continue;
      acc += wc[dy * 3 + dx] * xc[y * 64 + x2];
    }
  }
  out[idx] = acc;
}

// ---------------------------------------------------------------------------
// Kernel 3: MFMA flash attention, 32 queries/wave (dual Q fragment).
// No setprio, no forced occupancy bound (isolating R8's NaN).
// ---------------------------------------------------------------------------
__global__ __launch_bounds__(256) void attn_mfma(
    const unsigned short* __restrict__ Qkv,
    const unsigned short* __restrict__ Kt,
    float* __restrict__ Opart,
    float* __restrict__ lpart)
{
  const int h  = blockIdx.z;
  const int ks = blockIdx.y;
  const int tid  = threadIdx.x;
  const int w    = tid >> 6;
  const int lane = tid & 63;
  const int lq   = lane & 15;
  const int g    = lane >> 4;
  const int nqa  = blockIdx.x * 128 + w * 32 + lq;
  const int nqb  = nqa + 16;

  __shared__ unsigned short KbL[2][2048];
  __shared__ unsigned short VbL[2][2048];

  bf16x8 qfa, qfb;
  {
    const unsigned short* Qh = Qkv + h * HDIM * N_TOK;
    #pragma unroll
    for (int j = 0; j < 8; j++) {
      qfa[j] = (short)Qh[(8 * g + j) * N_TOK + nqa];
      qfb[j] = (short)Qh[(8 * g + j) * N_TOK + nqb];
    }
  }

  const unsigned short* KtH = Kt + (size_t)h * N_TOK * HDIM;
  const unsigned short* VH  = Qkv + (512 + h * HDIM) * N_TOK;
  const int kbase = ks * (N_TOK / KSPLIT);       // 1024 keys per split
  const int pr = 8 * (lq >> 2) + (lq & 3);

  const int skey  = (w & 1) * 4 + (w >> 1) * 32 + pr;
  const unsigned short* ksrc = &KtH[(size_t)(kbase + skey) * HDIM + 8 * g];
  const int sdrow = (w & 1) * 16 + lq;
  const unsigned short* vsrc = &VH[(size_t)sdrow * N_TOK + kbase + (w >> 1) * 32 + 8 * g];

  {
    const bf16x8 kr = *reinterpret_cast<const bf16x8*>(ksrc);
    const bf16x8 vr = *reinterpret_cast<const bf16x8*>(vsrc);
    *reinterpret_cast<bf16x8*>(&KbL[0][tid * 8]) = kr;
    *reinterpret_cast<bf16x8*>(&VbL[0][tid * 8]) = vr;
  }
  __syncthreads();

  f32x4 o0a = {0.f,0.f,0.f,0.f}, o1a = {0.f,0.f,0.f,0.f};
  f32x4 o0b = {0.f,0.f,0.f,0.f}, o1b = {0.f,0.f,0.f,0.f};
  f32x4 laa = {0.f,0.f,0.f,0.f}, lab = {0.f,0.f,0.f,0.f};
  const f32x4 zz = {0.f,0.f,0.f,0.f};
  constexpr int NT = (N_TOK / KSPLIT) / 64;      // 16 tiles

  int cur = 0;
  #pragma unroll 2
  for (int t = 0; t < NT; ++t) {
    bf16x8 kr = {}, vr = {};
    if (t + 1 < NT) {
      kr = *reinterpret_cast<const bf16x8*>(ksrc + (size_t)(t + 1) * 64 * HDIM);
      vr = *reinterpret_cast<const bf16x8*>(vsrc + (t + 1) * 64);
    }

    const unsigned short* kb = &KbL[cur][0];
    const unsigned short* vb = &VbL[cur][0];
    const bf16x8 kf0 = *reinterpret_cast<const bf16x8*>(&kb[lane * 8]);
    const bf16x8 kf1 = *reinterpret_cast<const bf16x8*>(&kb[lane * 8 + 512]);
    const bf16x8 kf2 = *reinterpret_cast<const bf16x8*>(&kb[lane * 8 + 1024]);
    const bf16x8 kf3 = *reinterpret_cast<const bf16x8*>(&kb[lane * 8 + 1536]);

    // ---- q-frag a ----
    f32x4 s0 = __builtin_amdgcn_mfma_f32_16x16x32_bf16(kf0, qfa, zz, 0, 0, 0);
    f32x4 s1 = __builtin_amdgcn_mfma_f32_16x16x32_bf16(kf1, qfa, zz, 0, 0, 0);
    f32x4 s2 = __builtin_amdgcn_mfma_f32_16x16x32_bf16(kf2, qfa, zz, 0, 0, 0);
    f32x4 s3 = __builtin_amdgcn_mfma_f32_16x16x32_bf16(kf3, qfa, zz, 0, 0, 0);
    #pragma unroll
    for (int r = 0; r < 4; r++) {
      s0[r] = fexp2(s0[r]); s1[r] = fexp2(s1[r]);
      s2[r] = fexp2(s2[r]); s3[r] = fexp2(s3[r]);
    }
    laa += s0; laa += s1; laa += s2; laa += s3;
    const u32x4 pua_a = { cvt_pk(s0[0], s0[1]), cvt_pk(s0[2], s0[3]),
                          cvt_pk(s1[0], s1[1]), cvt_pk(s1[2], s1[3]) };
    const u32x4 pub_a = { cvt_pk(s2[0], s2[1]), cvt_pk(s2[2], s2[3]),
                          cvt_pk(s3[0], s3[1]), cvt_pk(s3[2], s3[3]) };
    const bf16x8 pfa_a = __builtin_bit_cast(bf16x8, pua_a);
    const bf16x8 pfb_a = __builtin_bit_cast(bf16x8, pub_a);

    // ---- q-frag b ----
    f32x4 t0 = __builtin_amdgcn_mfma_f32_16x16x32_bf16(kf0, qfb, zz, 0, 0, 0);
    f32x4 t1 = __builtin_amdgcn_mfma_f32_16x16x32_bf16(kf1, qfb, zz, 0, 0, 0);
    f32x4 t2 = __builtin_amdgcn_mfma_f32_16x16x32_bf16(kf2, qfb, zz, 0, 0, 0);
    f32x4 t3 = __builtin_amdgcn_mfma_f32_16x16x32_bf16(kf3, qfb, zz, 0, 0, 0);
    #pragma unroll
    for (int r = 0; r < 4; r++) {
      t0[r] = fexp2(t0[r]); t1[r] = fexp2(t1[r]);
      t2[r] = fexp2(t2[r]); t3[r] = fexp2(t3[r]);
    }
    lab += t0; lab += t1; lab += t2; lab += t3;
    const u32x4 pua_b = { cvt_pk(t0[0], t0[1]), cvt_pk(t0[2], t0[3]),
                          cvt_pk(t1[0], t1[1]), cvt_pk(t1[2], t1[3]) };
    const u32x4 pub_b = { cvt_pk(t2[0], t2[1]), cvt_pk(t2[2], t2[3]),
                          cvt_pk(t3[0], t3[1]), cvt_pk(t3[2], t3[3]) };
    const bf16x8 pfa_b = __builtin_bit_cast(bf16x8, pua_b);
    const bf16x8 pfb_b = __builtin_bit_cast(bf16x8, pub_b);

    const bf16x8 vf0a = *reinterpret_cast<const bf16x8*>(&vb[lane * 8]);
    const bf16x8 vf1a = *reinterpret_cast<const bf16x8*>(&vb[lane * 8 + 512]);
    const bf16x8 vf0b = *reinterpret_cast<const bf16x8*>(&vb[lane * 8 + 1024]);
    const bf16x8 vf1b = *reinterpret_cast<const bf16x8*>(&vb[lane * 8 + 1536]);

    o0a = __builtin_amdgcn_mfma_f32_16x16x32_bf16(vf0a, pfa_a, o0a, 0, 0, 0);
    o0a = __builtin_amdgcn_mfma_f32_16x16x32_bf16(vf0b, pfb_a, o0a, 0, 0, 0);
    o1a = __builtin_amdgcn_mfma_f32_16x16x32_bf16(vf1a, pfa_a, o1a, 0, 0, 0);
    o1a = __builtin_amdgcn_mfma_f32_16x16x32_bf16(vf1b, pfb_a, o1a, 0, 0, 0);
    o0b = __builtin_amdgcn_mfma_f32_16x16x32_bf16(vf0a, pfa_b, o0b, 0, 0, 0);
    o0b = __builtin_amdgcn_mfma_f32_16x16x32_bf16(vf0b, pfb_b, o0b, 0, 0, 0);
    o1b = __builtin_amdgcn_mfma_f32_16x16x32_bf16(vf1a, pfa_b, o1b, 0, 0, 0);
    o1b = __builtin_amdgcn_mfma_f32_16x16x32_bf16(vf1b, pfb_b, o1b, 0, 0, 0);

    if (t + 1 < NT) {
      *reinterpret_cast<bf16x8*>(&KbL[cur ^ 1][tid * 8]) = kr;
      *reinterpret_cast<bf16x8*>(&VbL[cur ^ 1][tid * 8]) = vr;
    }
    __syncthreads();
    cur ^= 1;
  }

  float lsa = (laa[0] + laa[1]) + (laa[2] + laa[3]);
  lsa += __shfl_xor(lsa, 16);
  lsa += __shfl_xor(lsa, 32);
  float lsb = (lab[0] + lab[1]) + (lab[2] + lab[3]);
  lsb += __shfl_xor(lsb, 16);
  lsb += __shfl_xor(lsb, 32);

  const int ob = (ks * HEADS + h) * HDIM;
  #pragma unroll
  for (int r = 0; r < 4; r++) {
    Opart[(size_t)(ob + 4 * g + r) * N_TOK + nqa]      = o0a[r];
    Opart[(size_t)(ob + 16 + 4 * g + r) * N_TOK + nqa] = o1a[r];
    Opart[(size_t)(ob + 4 * g + r) * N_TOK + nqb]      = o0b[r];
    Opart[(size_t)(ob + 16 + 4 * g + r) * N_TOK + nqb] = o1b[r];
  }
  if (g == 0) {
    lpart[(ks * HEADS + h) * N_TOK + nqa] = lsa;
    lpart[(ks * HEADS + h) * N_TOK + nqb] = lsb;
  }
}

// ---------------------------------------------------------------------------
// Kernel 4: fused combine (sum partials, /L) + transpose + hi/lo split
// ---------------------------------------------------------------------------
__global__ __launch_bounds__(256) void combsplit(
    const float* __restrict__ Opart, const float* __restrict__ lpart,
    unsigned short* __restrict__ dhi, unsigned short* __restrict__ dlo)
{
  __shared__ float T[64][69];
  __shared__ float Linv[2][64];
  const int o0 = blockIdx.y * 64, n0 = blockIdx.x * 64;
  const int t = threadIdx.x;
  if (t < 128) {
    const int hl = t >> 6, nl = t & 63;
    const int hh = (o0 >> 5) + hl;
    float L = 0.f;
    #pragma unroll
    for (int ks = 0; ks < KSPLIT; ks++)
      L += lpart[(ks * HEADS + hh) * N_TOK + n0 + nl];
    Linv[hl][nl] = 1.f / L;
  }
  __syncthreads();
  {
    const int cl = t >> 2, ng = (t & 3) * 16;
    const int hrow = cl >> 5;
    #pragma unroll
    for (int jj = 0; jj < 4; jj++) {
      float4 a = make_float4(0.f, 0.f, 0.f, 0.f);
      #pragma unroll
      for (int ks = 0; ks < KSPLIT; ks++) {
        const float4 v = *reinterpret_cast<const float4*>(
            &Opart[(size_t)ks * C_DIM * N_TOK + (size_t)(o0 + cl) * N_TOK + n0 + ng + jj * 4]);
        a.x += v.x; a.y += v.y; a.z += v.z; a.w += v.w;
      }
      T[cl][ng + jj * 4 + 0] = a.x * Linv[hrow][ng + jj * 4 + 0];
      T[cl][ng + jj * 4 + 1] = a.y * Linv[hrow][ng + jj * 4 + 1];
      T[cl][ng + jj * 4 + 2] = a.z * Linv[hrow][ng + jj * 4 + 2];
      T[cl][ng + jj * 4 + 3] = a.w * Linv[hrow][ng + jj * 4 + 3];
    }
  }
  __syncthreads();
  {
    const int nl = t >> 2, cg = (t & 3) * 16;
    u16x8 h0, h1, l0, l1;
    #pragma unroll
    for (int j = 0; j < 8; j++) {
      const float v = T[cg + j][nl];
      h0[j] = f2bf(v); l0[j] = f2bf(v - bf2f(h0[j]));
    }
    #pragma unroll
    for (int j = 0; j < 8; j++) {
      const float v = T[cg + 8 + j][nl];
      h1[j] = f2bf(v); l1[j] = f2bf(v - bf2f(h1[j]));
    }
    const size_t base = (size_t)(n0 + nl) * C_DIM + o0 + cg;
    *reinterpret_cast<u16x8*>(&dhi[base])     = h0;
    *reinterpret_cast<u16x8*>(&dhi[base + 8]) = h1;
    *reinterpret_cast<u16x8*>(&dlo[base])     = l0;
    *reinterpret_cast<u16x8*>(&dlo[base + 8]) = l1;
  }
}

// ---------------------------------------------------------------------------
// Kernel 5: out projection (split-bf16, 3 MFMA), K-split 2, atomics onto conv.
// ---------------------------------------------------------------------------
__global__ __launch_bounds__(256) void out_mfma(
    const unsigned short* __restrict__ Whi, const unsigned short* __restrict__ Wlo,
    const unsigned short* __restrict__ Ohi, const unsigned short* __restrict__ Olo,
    float* __restrict__ out)
{
  const int n0 = blockIdx.x * 64;
  const int by = blockIdx.y;
  const int kb = blockIdx.z * 128;
  const int tid = threadIdx.x;
  const int w = tid >> 6, lane = tid & 63, lq = lane & 15, g = lane >> 4;
  const int c0 = by * 64 + w * 16;

  __shared__ unsigned short Bs[2][4096];

  const int e0l = tid & 63, e0f = tid >> 6;
  const unsigned short* s0p; const unsigned short* s1p;
  {
    const int lq_ = e0l & 15, g_ = e0l >> 4;
    const int f0 = e0f, f1 = e0f + 4;
    s0p = ((f0 & 1) ? Olo : Ohi) + (size_t)(n0 + (f0 >> 1) * 16 + lq_) * C_DIM + kb + 8 * g_;
    s1p = ((f1 & 1) ? Olo : Ohi) + (size_t)(n0 + (f1 >> 1) * 16 + lq_) * C_DIM + kb + 8 * g_;
  }
  const unsigned short* ahp = &Whi[(size_t)(768 + c0 + lq) * C_DIM + kb + 8 * g];
  const unsigned short* alp = &Wlo[(size_t)(768 + c0 + lq) * C_DIM + kb + 8 * g];

  f32x4 acc[4] = {{0.f,0.f,0.f,0.f},{0.f,0.f,0.f,0.f},{0.f,0.f,0.f,0.f},{0.f,0.f,0.f,0.f}};

  bf16x8 ah = *reinterpret_cast<const bf16x8*>(ahp);
  bf16x8 al = *reinterpret_cast<const bf16x8*>(alp);
  {
    const bf16x8 b0 = *reinterpret_cast<const bf16x8*>(s0p);
    const bf16x8 b1 = *reinterpret_cast<const bf16x8*>(s1p);
    *reinterpret_cast<bf16x8*>(&Bs[0][(size_t)tid * 8]) = b0;
    *reinterpret_cast<bf16x8*>(&Bs[0][((size_t)tid + 256) * 8]) = b1;
  }
  __syncthreads();

  int cur = 0;
  #pragma unroll
  for (int kk = 0; kk < 4; kk++) {
    bf16x8 nb0 = {}, nb1 = {}, nah = {}, nal = {};
    if (kk < 3) {
      const int ko = (kk + 1) * 32;
      nb0 = *reinterpret_cast<const bf16x8*>(s0p + ko);
      nb1 = *reinterpret_cast<const bf16x8*>(s1p + ko);
      nah = *reinterpret_cast<const bf16x8*>(ahp + ko);
      nal = *reinterpret_cast<const bf16x8*>(alp + ko);
    }
    #pragma unroll
    for (int ns = 0; ns < 4; ns++) {
      const bf16x8 bh = *reinterpret_cast<const bf16x8*>(&Bs[cur][(size_t)((ns * 2 + 0) * 64 + lane) * 8]);
      const bf16x8 bl = *reinterpret_cast<const bf16x8*>(&Bs[cur][(size_t)((ns * 2 + 1) * 64 + lane) * 8]);
      acc[ns] = __builtin_amdgcn_mfma_f32_16x16x32_bf16(ah, bh, acc[ns], 0, 0, 0);
      acc[ns] = __builtin_amdgcn_mfma_f32_16x16x32_bf16(ah, bl, acc[ns], 0, 0, 0);
      acc[ns] = __builtin_amdgcn_mfma_f32_16x16x32_bf16(al, bh, acc[ns], 0, 0, 0);
    }
    if (kk < 3) {
      *reinterpret_cast<bf16x8*>(&Bs[cur ^ 1][(size_t)tid * 8]) = nb0;
      *reinterpret_cast<bf16x8*>(&Bs[cur ^ 1][((size_t)tid + 256) * 8]) = nb1;
      ah = nah; al = nal;
    }
    __syncthreads();
    cur ^= 1;
  }

  #pragma unroll
  for (int ns = 0; ns < 4; ns++)
    #pragma unroll
    for (int r = 0; r < 4; r++)
      unsafeAtomicAdd(&out[(size_t)(c0 + 4 * g + r) * N_TOK + n0 + ns * 16 + lq], acc[ns][r]);
}

// ---------------------------------------------------------------------------
extern "C" void kernel_launch(void* const* d_in, const int* in_sizes, int n_in,
                              void* d_out, int out_size, void* d_ws, size_t ws_size,
                              hipStream_t stream) {
  const float* x  = (const float*)d_in[0];
  const float* wq = (const float*)d_in[1];
  const float* wk = (const float*)d_in[2];
  const float* wv = (const float*)d_in[3];
  const float* wo = (const float*)d_in[4];
  const float* wl = (const float*)d_in[5];
  float* out = (float*)d_out;

  float* Opart = (float*)d_ws;                                  // 4*256*4096 f
  float* lpart = Opart + (size_t)KSPLIT * C_DIM * N_TOK;        // 4*8*4096 f
  unsigned short* Qkv = (unsigned short*)(lpart + KSPLIT * HEADS * N_TOK);  // 768*4096
  unsigned short* Kt  = Qkv + 768 * N_TOK;                      // 8*4096*32
  unsigned short* Whi = Kt + (size_t)HEADS * N_TOK * HDIM;      // 1024*256
  unsigned short* Wlo = Whi + 1024 * C_DIM;
  unsigned short* Xhi = Wlo + 1024 * C_DIM;                     // 4096*256
  unsigned short* Xlo = Xhi + (size_t)N_TOK * C_DIM;
  unsigned short* Ohi = Xlo + (size_t)N_TOK * C_DIM;
  unsigned short* Olo = Ohi + (size_t)N_TOK * C_DIM;            // ~35.1 MB total

  wsplit<<<256, 256, 0, stream>>>(wq, wk, wv, wo, Whi, Wlo);
  tsplit<<<dim3(64, 4), 256, 0, stream>>>(x, Xhi, Xlo);
  qkv_mfma<<<dim3(64, 12), 256, 0, stream>>>(Whi, Wlo, Xhi, Xlo, Qkv, Kt);
  dwconv_kernel<<<4096, 256, 0, stream>>>(x, wl, out);
  attn_mfma<<<dim3(32, KSPLIT, HEADS), 256, 0, stream>>>(Qkv, Kt, Opart, lpart);
  combsplit<<<dim3(64, 4), 256, 0, stream>>>(Opart, lpart, Ohi, Olo);
  out_mfma<<<dim3(64, 4, 2), 256, 0, stream>>>(Whi, Wlo, Ohi, Olo, out);
}

// Round 10
// 131.874 us; speedup vs baseline: 1.0808x; 1.0808x over previous
//
#include <hip/hip_runtime.h>

#define N_TOK 4096
#define C_DIM 256
#define HEADS 8
#define HDIM  32
#define KSPLIT 8
#define QSCALE 0.17677669529663687f
#define L2E    1.4426950408889634f

typedef __attribute__((ext_vector_type(8))) short bf16x8;
typedef __attribute__((ext_vector_type(4))) float f32x4;
typedef __attribute__((ext_vector_type(4))) unsigned int u32x4;
typedef __attribute__((ext_vector_type(8))) unsigned short u16x8;

static __device__ __forceinline__ unsigned short f2bf(float f) {
  union { float f; unsigned int u; } c; c.f = f;
  return (unsigned short)((c.u + 0x8000u) >> 16);
}
static __device__ __forceinline__ float bf2f(unsigned short u) {
  union { unsigned int i; float f; } c; c.i = ((unsigned int)u) << 16;
  return c.f;
}
static __device__ __forceinline__ float fexp2(float x) {
  float r; asm("v_exp_f32 %0, %1" : "=v"(r) : "v"(x)); return r;
}
static __device__ __forceinline__ unsigned int cvt_pk(float lo, float hi) {
  unsigned int r; asm("v_cvt_pk_bf16_f32 %0, %1, %2" : "=v"(r) : "v"(lo), "v"(hi)); return r;
}

// ---------------------------------------------------------------------------
// Kernel 0: prep = {W -> bf16 (wq scaled)} ∪ {x transpose -> Xb bf16 [n][c]}
// blocks 0..255: W convert; blocks 256..511: x tile transpose.
// ---------------------------------------------------------------------------
__global__ __launch_bounds__(256) void prep(
    const float* __restrict__ wq, const float* __restrict__ wk,
    const float* __restrict__ wv, const float* __restrict__ wo,
    const float* __restrict__ x,
    unsigned short* __restrict__ Wb, unsigned short* __restrict__ Xb)
{
  __shared__ float T[64][69];
  const int bid = blockIdx.x;
  const int t = threadIdx.x;
  if (bid < 256) {
    const int idx = (bid * 256 + t) * 4;
    const int r   = idx >> 8;
    const float* src; int off; float scl = 1.f;
    if (r < 256)      { src = wq; off = idx;          scl = QSCALE * L2E; }
    else if (r < 512) { src = wk; off = idx - 65536;  }
    else if (r < 768) { src = wv; off = idx - 131072; }
    else              { src = wo; off = idx - 196608; }
    float4 v = *reinterpret_cast<const float4*>(&src[off]);
    ushort4 h;
    h.x = f2bf(v.x * scl); h.y = f2bf(v.y * scl);
    h.z = f2bf(v.z * scl); h.w = f2bf(v.w * scl);
    *reinterpret_cast<ushort4*>(&Wb[idx]) = h;
  } else {
    const int b2 = bid - 256;
    const int n0 = (b2 & 63) * 64, c0 = (b2 >> 6) * 64;
    {
      const int cl = t >> 2, ng = (t & 3) * 16;
      #pragma unroll
      for (int jj = 0; jj < 4; jj++) {
        const float4 v = *reinterpret_cast<const float4*>(&x[(c0 + cl) * N_TOK + n0 + ng + jj * 4]);
        T[cl][ng + jj * 4 + 0] = v.x; T[cl][ng + jj * 4 + 1] = v.y;
        T[cl][ng + jj * 4 + 2] = v.z; T[cl][ng + jj * 4 + 3] = v.w;
      }
    }
    __syncthreads();
    {
      const int nl = t >> 2, cg = (t & 3) * 16;
      u16x8 h0, h1;
      #pragma unroll
      for (int j = 0; j < 8; j++) h0[j] = f2bf(T[cg + j][nl]);
      #pragma unroll
      for (int j = 0; j < 8; j++) h1[j] = f2bf(T[cg + 8 + j][nl]);
      const size_t base = (size_t)(n0 + nl) * C_DIM + c0 + cg;
      *reinterpret_cast<u16x8*>(&Xb[base])     = h0;
      *reinterpret_cast<u16x8*>(&Xb[base + 8]) = h1;
    }
  }
}

// ---------------------------------------------------------------------------
// Kernel 1: QKV projection, single bf16, LDS-staged B, BK=64 phases.
// B tile staged in fragment-read order (entry e at ushort e*8, zero conflict).
// K rows written directly transposed to Kt[h][n][d].
// ---------------------------------------------------------------------------
__global__ __launch_bounds__(256) void qkv_mfma(
    const unsigned short* __restrict__ Wb,
    const unsigned short* __restrict__ Xb,
    unsigned short* __restrict__ Qkv, unsigned short* __restrict__ Kt)
{
  const int n0 = blockIdx.x * 64;
  const int by = blockIdx.y;                 // 0..11
  const int tid = threadIdx.x;
  const int w = tid >> 6, lane = tid & 63, lq = lane & 15, g = lane >> 4;
  const int o0 = by * 64 + w * 16;

  __shared__ unsigned short Bs[2][4096];     // 8KB per buffer (64n x 64k)

  const int lane_ = tid & 63, ns_ = tid >> 6;
  const unsigned short* sp = Xb + (size_t)(n0 + ns_ * 16 + (lane_ & 15)) * C_DIM + 8 * (lane_ >> 4);
  const unsigned short* ahp = &Wb[(size_t)(o0 + lq) * C_DIM + 8 * g];

  f32x4 acc[4] = {{0.f,0.f,0.f,0.f},{0.f,0.f,0.f,0.f},{0.f,0.f,0.f,0.f},{0.f,0.f,0.f,0.f}};

  bf16x8 ah0 = *reinterpret_cast<const bf16x8*>(ahp);
  bf16x8 ah1 = *reinterpret_cast<const bf16x8*>(ahp + 32);
  {
    const bf16x8 b0 = *reinterpret_cast<const bf16x8*>(sp);
    const bf16x8 b1 = *reinterpret_cast<const bf16x8*>(sp + 32);
    *reinterpret_cast<bf16x8*>(&Bs[0][(size_t)tid * 8]) = b0;
    *reinterpret_cast<bf16x8*>(&Bs[0][((size_t)tid + 256) * 8]) = b1;
  }
  __syncthreads();

  int cur = 0;
  #pragma unroll
  for (int kk = 0; kk < 4; kk++) {
    bf16x8 nb0 = {}, nb1 = {}, nah0 = {}, nah1 = {};
    if (kk < 3) {
      const int ko = (kk + 1) * 64;
      nb0  = *reinterpret_cast<const bf16x8*>(sp + ko);
      nb1  = *reinterpret_cast<const bf16x8*>(sp + ko + 32);
      nah0 = *reinterpret_cast<const bf16x8*>(ahp + ko);
      nah1 = *reinterpret_cast<const bf16x8*>(ahp + ko + 32);
    }
    #pragma unroll
    for (int ns = 0; ns < 4; ns++) {
      const bf16x8 bh0 = *reinterpret_cast<const bf16x8*>(&Bs[cur][(size_t)(ns * 64 + lane) * 8]);
      const bf16x8 bh1 = *reinterpret_cast<const bf16x8*>(&Bs[cur][(size_t)((ns + 4) * 64 + lane) * 8]);
      acc[ns] = __builtin_amdgcn_mfma_f32_16x16x32_bf16(ah0, bh0, acc[ns], 0, 0, 0);
      acc[ns] = __builtin_amdgcn_mfma_f32_16x16x32_bf16(ah1, bh1, acc[ns], 0, 0, 0);
    }
    if (kk < 3) {
      *reinterpret_cast<bf16x8*>(&Bs[cur ^ 1][(size_t)tid * 8]) = nb0;
      *reinterpret_cast<bf16x8*>(&Bs[cur ^ 1][((size_t)tid + 256) * 8]) = nb1;
      ah0 = nah0; ah1 = nah1;
    }
    __syncthreads();
    cur ^= 1;
  }

  if (by < 4 || by >= 8) {
    const int orow0 = (by < 4 ? by * 64 : (by - 8) * 64 + 512) + w * 16 + 4 * g;
    #pragma unroll
    for (int ns = 0; ns < 4; ns++)
      #pragma unroll
      for (int r = 0; r < 4; r++)
        Qkv[(size_t)(orow0 + r) * N_TOK + n0 + ns * 16 + lq] = f2bf(acc[ns][r]);
  } else {
    const int ok0 = (by - 4) * 64 + w * 16 + 4 * g;
    const int hh = ok0 >> 5, d0 = ok0 & 31;
    #pragma unroll
    for (int ns = 0; ns < 4; ns++) {
      ushort4 u;
      u.x = f2bf(acc[ns][0]); u.y = f2bf(acc[ns][1]);
      u.z = f2bf(acc[ns][2]); u.w = f2bf(acc[ns][3]);
      *reinterpret_cast<ushort4*>(&Kt[((size_t)hh * N_TOK + n0 + ns * 16 + lq) * HDIM + d0]) = u;
    }
  }
}

// ---------------------------------------------------------------------------
// Kernel 2: MFMA flash attention (R9-proven dual-Q structure), KSPLIT=8,
// bf16 partials. No setprio, no forced occupancy bound.
// ---------------------------------------------------------------------------
__global__ __launch_bounds__(256) void attn_mfma(
    const unsigned short* __restrict__ Qkv,
    const unsigned short* __restrict__ Kt,
    unsigned short* __restrict__ Opb,
    float* __restrict__ lpart)
{
  const int h  = blockIdx.z;
  const int ks = blockIdx.y;
  const int tid  = threadIdx.x;
  const int w    = tid >> 6;
  const int lane = tid & 63;
  const int lq   = lane & 15;
  const int g    = lane >> 4;
  const int nqa  = blockIdx.x * 128 + w * 32 + lq;
  const int nqb  = nqa + 16;

  __shared__ unsigned short KbL[2][2048];
  __shared__ unsigned short VbL[2][2048];

  bf16x8 qfa, qfb;
  {
    const unsigned short* Qh = Qkv + h * HDIM * N_TOK;
    #pragma unroll
    for (int j = 0; j < 8; j++) {
      qfa[j] = (short)Qh[(8 * g + j) * N_TOK + nqa];
      qfb[j] = (short)Qh[(8 * g + j) * N_TOK + nqb];
    }
  }

  const unsigned short* KtH = Kt + (size_t)h * N_TOK * HDIM;
  const unsigned short* VH  = Qkv + (512 + h * HDIM) * N_TOK;
  const int kbase = ks * (N_TOK / KSPLIT);       // 512 keys per split
  const int pr = 8 * (lq >> 2) + (lq & 3);

  const int skey  = (w & 1) * 4 + (w >> 1) * 32 + pr;
  const unsigned short* ksrc = &KtH[(size_t)(kbase + skey) * HDIM + 8 * g];
  const int sdrow = (w & 1) * 16 + lq;
  const unsigned short* vsrc = &VH[(size_t)sdrow * N_TOK + kbase + (w >> 1) * 32 + 8 * g];

  {
    const bf16x8 kr = *reinterpret_cast<const bf16x8*>(ksrc);
    const bf16x8 vr = *reinterpret_cast<const bf16x8*>(vsrc);
    *reinterpret_cast<bf16x8*>(&KbL[0][tid * 8]) = kr;
    *reinterpret_cast<bf16x8*>(&VbL[0][tid * 8]) = vr;
  }
  __syncthreads();

  f32x4 o0a = {0.f,0.f,0.f,0.f}, o1a = {0.f,0.f,0.f,0.f};
  f32x4 o0b = {0.f,0.f,0.f,0.f}, o1b = {0.f,0.f,0.f,0.f};
  f32x4 laa = {0.f,0.f,0.f,0.f}, lab = {0.f,0.f,0.f,0.f};
  const f32x4 zz = {0.f,0.f,0.f,0.f};
  constexpr int NT = (N_TOK / KSPLIT) / 64;      // 8 tiles

  int cur = 0;
  #pragma unroll 2
  for (int t = 0; t < NT; ++t) {
    bf16x8 kr = {}, vr = {};
    if (t + 1 < NT) {
      kr = *reinterpret_cast<const bf16x8*>(ksrc + (size_t)(t + 1) * 64 * HDIM);
      vr = *reinterpret_cast<const bf16x8*>(vsrc + (t + 1) * 64);
    }

    const unsigned short* kb = &KbL[cur][0];
    const unsigned short* vb = &VbL[cur][0];
    const bf16x8 kf0 = *reinterpret_cast<const bf16x8*>(&kb[lane * 8]);
    const bf16x8 kf1 = *reinterpret_cast<const bf16x8*>(&kb[lane * 8 + 512]);
    const bf16x8 kf2 = *reinterpret_cast<const bf16x8*>(&kb[lane * 8 + 1024]);
    const bf16x8 kf3 = *reinterpret_cast<const bf16x8*>(&kb[lane * 8 + 1536]);

    // ---- q-frag a ----
    f32x4 s0 = __builtin_amdgcn_mfma_f32_16x16x32_bf16(kf0, qfa, zz, 0, 0, 0);
    f32x4 s1 = __builtin_amdgcn_mfma_f32_16x16x32_bf16(kf1, qfa, zz, 0, 0, 0);
    f32x4 s2 = __builtin_amdgcn_mfma_f32_16x16x32_bf16(kf2, qfa, zz, 0, 0, 0);
    f32x4 s3 = __builtin_amdgcn_mfma_f32_16x16x32_bf16(kf3, qfa, zz, 0, 0, 0);
    #pragma unroll
    for (int r = 0; r < 4; r++) {
      s0[r] = fexp2(s0[r]); s1[r] = fexp2(s1[r]);
      s2[r] = fexp2(s2[r]); s3[r] = fexp2(s3[r]);
    }
    laa += s0; laa += s1; laa += s2; laa += s3;
    const u32x4 pua_a = { cvt_pk(s0[0], s0[1]), cvt_pk(s0[2], s0[3]),
                          cvt_pk(s1[0], s1[1]), cvt_pk(s1[2], s1[3]) };
    const u32x4 pub_a = { cvt_pk(s2[0], s2[1]), cvt_pk(s2[2], s2[3]),
                          cvt_pk(s3[0], s3[1]), cvt_pk(s3[2], s3[3]) };
    const bf16x8 pfa_a = __builtin_bit_cast(bf16x8, pua_a);
    const bf16x8 pfb_a = __builtin_bit_cast(bf16x8, pub_a);

    // ---- q-frag b ----
    f32x4 t0 = __builtin_amdgcn_mfma_f32_16x16x32_bf16(kf0, qfb, zz, 0, 0, 0);
    f32x4 t1 = __builtin_amdgcn_mfma_f32_16x16x32_bf16(kf1, qfb, zz, 0, 0, 0);
    f32x4 t2 = __builtin_amdgcn_mfma_f32_16x16x32_bf16(kf2, qfb, zz, 0, 0, 0);
    f32x4 t3 = __builtin_amdgcn_mfma_f32_16x16x32_bf16(kf3, qfb, zz, 0, 0, 0);
    #pragma unroll
    for (int r = 0; r < 4; r++) {
      t0[r] = fexp2(t0[r]); t1[r] = fexp2(t1[r]);
      t2[r] = fexp2(t2[r]); t3[r] = fexp2(t3[r]);
    }
    lab += t0; lab += t1; lab += t2; lab += t3;
    const u32x4 pua_b = { cvt_pk(t0[0], t0[1]), cvt_pk(t0[2], t0[3]),
                          cvt_pk(t1[0], t1[1]), cvt_pk(t1[2], t1[3]) };
    const u32x4 pub_b = { cvt_pk(t2[0], t2[1]), cvt_pk(t2[2], t2[3]),
                          cvt_pk(t3[0], t3[1]), cvt_pk(t3[2], t3[3]) };
    const bf16x8 pfa_b = __builtin_bit_cast(bf16x8, pua_b);
    const bf16x8 pfb_b = __builtin_bit_cast(bf16x8, pub_b);

    const bf16x8 vf0a = *reinterpret_cast<const bf16x8*>(&vb[lane * 8]);
    const bf16x8 vf1a = *reinterpret_cast<const bf16x8*>(&vb[lane * 8 + 512]);
    const bf16x8 vf0b = *reinterpret_cast<const bf16x8*>(&vb[lane * 8 + 1024]);
    const bf16x8 vf1b = *reinterpret_cast<const bf16x8*>(&vb[lane * 8 + 1536]);

    o0a = __builtin_amdgcn_mfma_f32_16x16x32_bf16(vf0a, pfa_a, o0a, 0, 0, 0);
    o0a = __builtin_amdgcn_mfma_f32_16x16x32_bf16(vf0b, pfb_a, o0a, 0, 0, 0);
    o1a = __builtin_amdgcn_mfma_f32_16x16x32_bf16(vf1a, pfa_a, o1a, 0, 0, 0);
    o1a = __builtin_amdgcn_mfma_f32_16x16x32_bf16(vf1b, pfb_a, o1a, 0, 0, 0);
    o0b = __builtin_amdgcn_mfma_f32_16x16x32_bf16(vf0a, pfa_b, o0b, 0, 0, 0);
    o0b = __builtin_amdgcn_mfma_f32_16x16x32_bf16(vf0b, pfb_b, o0b, 0, 0, 0);
    o1b = __builtin_amdgcn_mfma_f32_16x16x32_bf16(vf1a, pfa_b, o1b, 0, 0, 0);
    o1b = __builtin_amdgcn_mfma_f32_16x16x32_bf16(vf1b, pfb_b, o1b, 0, 0, 0);

    if (t + 1 < NT) {
      *reinterpret_cast<bf16x8*>(&KbL[cur ^ 1][tid * 8]) = kr;
      *reinterpret_cast<bf16x8*>(&VbL[cur ^ 1][tid * 8]) = vr;
    }
    __syncthreads();
    cur ^= 1;
  }

  float lsa = (laa[0] + laa[1]) + (laa[2] + laa[3]);
  lsa += __shfl_xor(lsa, 16);
  lsa += __shfl_xor(lsa, 32);
  float lsb = (lab[0] + lab[1]) + (lab[2] + lab[3]);
  lsb += __shfl_xor(lsb, 16);
  lsb += __shfl_xor(lsb, 32);

  const int ob = (ks * HEADS + h) * HDIM;
  #pragma unroll
  for (int r = 0; r < 4; r++) {
    Opb[(size_t)(ob + 4 * g + r) * N_TOK + nqa]      = f2bf(o0a[r]);
    Opb[(size_t)(ob + 16 + 4 * g + r) * N_TOK + nqa] = f2bf(o1a[r]);
    Opb[(size_t)(ob + 4 * g + r) * N_TOK + nqb]      = f2bf(o0b[r]);
    Opb[(size_t)(ob + 16 + 4 * g + r) * N_TOK + nqb] = f2bf(o1b[r]);
  }
  if (g == 0) {
    lpart[(ks * HEADS + h) * N_TOK + nqa] = lsa;
    lpart[(ks * HEADS + h) * N_TOK + nqb] = lsb;
  }
}

// ---------------------------------------------------------------------------
// Kernel 3: combine (sum bf16 partials, /L) + transpose -> Ob bf16 [n][o]
// ---------------------------------------------------------------------------
__global__ __launch_bounds__(256) void combsplit(
    const unsigned short* __restrict__ Opb, const float* __restrict__ lpart,
    unsigned short* __restrict__ Ob)
{
  __shared__ float T[64][69];
  __shared__ float Linv[2][64];
  const int o0 = blockIdx.y * 64, n0 = blockIdx.x * 64;
  const int t = threadIdx.x;
  if (t < 128) {
    const int hl = t >> 6, nl = t & 63;
    const int hh = (o0 >> 5) + hl;
    float L = 0.f;
    #pragma unroll
    for (int ks = 0; ks < KSPLIT; ks++)
      L += lpart[(ks * HEADS + hh) * N_TOK + n0 + nl];
    Linv[hl][nl] = 1.f / L;
  }
  __syncthreads();
  {
    const int cl = t >> 2, ng = (t & 3) * 16;
    const int hrow = cl >> 5;
    #pragma unroll
    for (int jj = 0; jj < 4; jj++) {
      float a0 = 0.f, a1 = 0.f, a2 = 0.f, a3 = 0.f;
      #pragma unroll
      for (int ks = 0; ks < KSPLIT; ks++) {
        const ushort4 u = *reinterpret_cast<const ushort4*>(
            &Opb[(size_t)ks * C_DIM * N_TOK + (size_t)(o0 + cl) * N_TOK + n0 + ng + jj * 4]);
        a0 += bf2f(u.x); a1 += bf2f(u.y); a2 += bf2f(u.z); a3 += bf2f(u.w);
      }
      T[cl][ng + jj * 4 + 0] = a0 * Linv[hrow][ng + jj * 4 + 0];
      T[cl][ng + jj * 4 + 1] = a1 * Linv[hrow][ng + jj * 4 + 1];
      T[cl][ng + jj * 4 + 2] = a2 * Linv[hrow][ng + jj * 4 + 2];
      T[cl][ng + jj * 4 + 3] = a3 * Linv[hrow][ng + jj * 4 + 3];
    }
  }
  __syncthreads();
  {
    const int nl = t >> 2, cg = (t & 3) * 16;
    u16x8 h0, h1;
    #pragma unroll
    for (int j = 0; j < 8; j++) h0[j] = f2bf(T[cg + j][nl]);
    #pragma unroll
    for (int j = 0; j < 8; j++) h1[j] = f2bf(T[cg + 8 + j][nl]);
    const size_t base = (size_t)(n0 + nl) * C_DIM + o0 + cg;
    *reinterpret_cast<u16x8*>(&Ob[base])     = h0;
    *reinterpret_cast<u16x8*>(&Ob[base + 8]) = h1;
  }
}

// ---------------------------------------------------------------------------
// Kernel 4: out projection (single bf16) + fused depthwise 3x3 conv epilogue.
// out = conv(x,wl) + wo @ outb  — plain stores, no atomics, no dwconv kernel.
// ---------------------------------------------------------------------------
__global__ __launch_bounds__(256) void out_mfma(
    const unsigned short* __restrict__ Wb,
    const unsigned short* __restrict__ Ob,
    const float* __restrict__ x, const float* __restrict__ wl,
    float* __restrict__ out)
{
  const int n0 = blockIdx.x * 64;
  const int by = blockIdx.y;
  const int tid = threadIdx.x;
  const int w = tid >> 6, lane = tid & 63, lq = lane & 15, g = lane >> 4;
  const int c0 = by * 64 + w * 16;

  __shared__ unsigned short Bs[2][4096];

  const int lane_ = tid & 63, ns_ = tid >> 6;
  const unsigned short* sp = Ob + (size_t)(n0 + ns_ * 16 + (lane_ & 15)) * C_DIM + 8 * (lane_ >> 4);
  const unsigned short* ahp = &Wb[(size_t)(768 + c0 + lq) * C_DIM + 8 * g];

  f32x4 acc[4] = {{0.f,0.f,0.f,0.f},{0.f,0.f,0.f,0.f},{0.f,0.f,0.f,0.f},{0.f,0.f,0.f,0.f}};

  bf16x8 ah0 = *reinterpret_cast<const bf16x8*>(ahp);
  bf16x8 ah1 = *reinterpret_cast<const bf16x8*>(ahp + 32);
  {
    const bf16x8 b0 = *reinterpret_cast<const bf16x8*>(sp);
    const bf16x8 b1 = *reinterpret_cast<const bf16x8*>(sp + 32);
    *reinterpret_cast<bf16x8*>(&Bs[0][(size_t)tid * 8]) = b0;
    *reinterpret_cast<bf16x8*>(&Bs[0][((size_t)tid + 256) * 8]) = b1;
  }
  __syncthreads();

  int cur = 0;
  #pragma unroll
  for (int kk = 0; kk < 4; kk++) {
    bf16x8 nb0 = {}, nb1 = {}, nah0 = {}, nah1 = {};
    if (kk < 3) {
      const int ko = (kk + 1) * 64;
      nb0  = *reinterpret_cast<const bf16x8*>(sp + ko);
      nb1  = *reinterpret_cast<const bf16x8*>(sp + ko + 32);
      nah0 = *reinterpret_cast<const bf16x8*>(ahp + ko);
      nah1 = *reinterpret_cast<const bf16x8*>(ahp + ko + 32);
    }
    #pragma unroll
    for (int ns = 0; ns < 4; ns++) {
      const bf16x8 bh0 = *reinterpret_cast<const bf16x8*>(&Bs[cur][(size_t)(ns * 64 + lane) * 8]);
      const bf16x8 bh1 = *reinterpret_cast<const bf16x8*>(&Bs[cur][(size_t)((ns + 4) * 64 + lane) * 8]);
      acc[ns] = __builtin_amdgcn_mfma_f32_16x16x32_bf16(ah0, bh0, acc[ns], 0, 0, 0);
      acc[ns] = __builtin_amdgcn_mfma_f32_16x16x32_bf16(ah1, bh1, acc[ns], 0, 0, 0);
    }
    if (kk < 3) {
      *reinterpret_cast<bf16x8*>(&Bs[cur ^ 1][(size_t)tid * 8]) = nb0;
      *reinterpret_cast<bf16x8*>(&Bs[cur ^ 1][((size_t)tid + 256) * 8]) = nb1;
      ah0 = nah0; ah1 = nah1;
    }
    __syncthreads();
    cur ^= 1;
  }

  // fused depthwise conv epilogue: this block's n-range is image row yy = bx
  const int yy = blockIdx.x;
  #pragma unroll
  for (int ns = 0; ns < 4; ns++) {
    #pragma unroll
    for (int r = 0; r < 4; r++) {
      const int c = c0 + 4 * g + r;
      const int n = n0 + ns * 16 + lq;
      const int xx = n & 63;
      const float* xc  = x + (size_t)c * 4096;
      const float* wl9 = wl + (size_t)c * 9;
      float cv = 0.f;
      #pragma unroll
      for (int dy = 0; dy < 3; dy++) {
        const int y2 = yy + dy - 1;
        if (y2 < 0 || y2 > 63) continue;
        #pragma unroll
        for (int dx = 0; dx < 3; dx++) {
          const int x2 = xx + dx - 1;
          if (x2 < 0 || x2 > 63) continue;
          cv += wl9[dy * 3 + dx] * xc[y2 * 64 + x2];
        }
      }
      out[(size_t)c * N_TOK + n] = cv + acc[ns][r];
    }
  }
}

// ---------------------------------------------------------------------------
extern "C" void kernel_launch(void* const* d_in, const int* in_sizes, int n_in,
                              void* d_out, int out_size, void* d_ws, size_t ws_size,
                              hipStream_t stream) {
  const float* x  = (const float*)d_in[0];
  const float* wq = (const float*)d_in[1];
  const float* wk = (const float*)d_in[2];
  const float* wv = (const float*)d_in[3];
  const float* wo = (const float*)d_in[4];
  const float* wl = (const float*)d_in[5];
  float* out = (float*)d_out;

  unsigned short* Opb = (unsigned short*)d_ws;                  // 8*256*4096 us
  float* lpart = (float*)(Opb + (size_t)KSPLIT * C_DIM * N_TOK);// 8*8*4096 f
  unsigned short* Qkv = (unsigned short*)(lpart + KSPLIT * HEADS * N_TOK);
  unsigned short* Kt  = Qkv + 768 * N_TOK;                      // 8*4096*32
  unsigned short* Wb  = Kt + (size_t)HEADS * N_TOK * HDIM;      // 1024*256
  unsigned short* Xb  = Wb + 1024 * C_DIM;                      // 4096*256
  unsigned short* Ob  = Xb + (size_t)N_TOK * C_DIM;             // 4096*256
  // total ~31 MB

  prep<<<512, 256, 0, stream>>>(wq, wk, wv, wo, x, Wb, Xb);
  qkv_mfma<<<dim3(64, 12), 256, 0, stream>>>(Wb, Xb, Qkv, Kt);
  attn_mfma<<<dim3(32, KSPLIT, HEADS), 256, 0, stream>>>(Qkv, Kt, Opb, lpart);
  combsplit<<<dim3(64, 4), 256, 0, stream>>>(Opb, lpart, Ob);
  out_mfma<<<dim3(64, 4), 256, 0, stream>>>(Wb, Ob, x, wl, out);
}

// Round 11
// 126.009 us; speedup vs baseline: 1.1311x; 1.0465x over previous
//
#include <hip/hip_runtime.h>

#define N_TOK 4096
#define C_DIM 256
#define HEADS 8
#define HDIM  32
#define KSPLIT 4
#define QSCALE 0.17677669529663687f
#define L2E    1.4426950408889634f

typedef __attribute__((ext_vector_type(8))) short bf16x8;
typedef __attribute__((ext_vector_type(4))) float f32x4;
typedef __attribute__((ext_vector_type(4))) unsigned int u32x4;
typedef __attribute__((ext_vector_type(8))) unsigned short u16x8;

static __device__ __forceinline__ unsigned short f2bf(float f) {
  union { float f; unsigned int u; } c; c.f = f;
  return (unsigned short)((c.u + 0x8000u) >> 16);
}
static __device__ __forceinline__ float bf2f(unsigned short u) {
  union { unsigned int i; float f; } c; c.i = ((unsigned int)u) << 16;
  return c.f;
}
static __device__ __forceinline__ float fexp2(float x) {
  float r; asm("v_exp_f32 %0, %1" : "=v"(r) : "v"(x)); return r;
}
static __device__ __forceinline__ unsigned int cvt_pk(float lo, float hi) {
  unsigned int r; asm("v_cvt_pk_bf16_f32 %0, %1, %2" : "=v"(r) : "v"(lo), "v"(hi)); return r;
}

// ---------------------------------------------------------------------------
// Kernel 0: prep = {W -> bf16 (wq scaled)} ∪ {x transpose -> Xb bf16 [n][c]}
// ---------------------------------------------------------------------------
__global__ __launch_bounds__(256) void prep(
    const float* __restrict__ wq, const float* __restrict__ wk,
    const float* __restrict__ wv, const float* __restrict__ wo,
    const float* __restrict__ x,
    unsigned short* __restrict__ Wb, unsigned short* __restrict__ Xb)
{
  __shared__ float T[64][69];
  const int bid = blockIdx.x;
  const int t = threadIdx.x;
  if (bid < 256) {
    const int idx = (bid * 256 + t) * 4;
    const int r   = idx >> 8;
    const float* src; int off; float scl = 1.f;
    if (r < 256)      { src = wq; off = idx;          scl = QSCALE * L2E; }
    else if (r < 512) { src = wk; off = idx - 65536;  }
    else if (r < 768) { src = wv; off = idx - 131072; }
    else              { src = wo; off = idx - 196608; }
    float4 v = *reinterpret_cast<const float4*>(&src[off]);
    ushort4 h;
    h.x = f2bf(v.x * scl); h.y = f2bf(v.y * scl);
    h.z = f2bf(v.z * scl); h.w = f2bf(v.w * scl);
    *reinterpret_cast<ushort4*>(&Wb[idx]) = h;
  } else {
    const int b2 = bid - 256;
    const int n0 = (b2 & 63) * 64, c0 = (b2 >> 6) * 64;
    {
      const int cl = t >> 2, ng = (t & 3) * 16;
      #pragma unroll
      for (int jj = 0; jj < 4; jj++) {
        const float4 v = *reinterpret_cast<const float4*>(&x[(c0 + cl) * N_TOK + n0 + ng + jj * 4]);
        T[cl][ng + jj * 4 + 0] = v.x; T[cl][ng + jj * 4 + 1] = v.y;
        T[cl][ng + jj * 4 + 2] = v.z; T[cl][ng + jj * 4 + 3] = v.w;
      }
    }
    __syncthreads();
    {
      const int nl = t >> 2, cg = (t & 3) * 16;
      u16x8 h0, h1;
      #pragma unroll
      for (int j = 0; j < 8; j++) h0[j] = f2bf(T[cg + j][nl]);
      #pragma unroll
      for (int j = 0; j < 8; j++) h1[j] = f2bf(T[cg + 8 + j][nl]);
      const size_t base = (size_t)(n0 + nl) * C_DIM + c0 + cg;
      *reinterpret_cast<u16x8*>(&Xb[base])     = h0;
      *reinterpret_cast<u16x8*>(&Xb[base + 8]) = h1;
    }
  }
}

// ---------------------------------------------------------------------------
// Kernel 1: QKV projection, single bf16, LDS-staged B, BK=64 phases.
// K rows written directly transposed to Kt[h][n][d].
// ---------------------------------------------------------------------------
__global__ __launch_bounds__(256) void qkv_mfma(
    const unsigned short* __restrict__ Wb,
    const unsigned short* __restrict__ Xb,
    unsigned short* __restrict__ Qkv, unsigned short* __restrict__ Kt)
{
  const int n0 = blockIdx.x * 64;
  const int by = blockIdx.y;                 // 0..11
  const int tid = threadIdx.x;
  const int w = tid >> 6, lane = tid & 63, lq = lane & 15, g = lane >> 4;
  const int o0 = by * 64 + w * 16;

  __shared__ unsigned short Bs[2][4096];     // 8KB per buffer (64n x 64k)

  const int lane_ = tid & 63, ns_ = tid >> 6;
  const unsigned short* sp = Xb + (size_t)(n0 + ns_ * 16 + (lane_ & 15)) * C_DIM + 8 * (lane_ >> 4);
  const unsigned short* ahp = &Wb[(size_t)(o0 + lq) * C_DIM + 8 * g];

  f32x4 acc[4] = {{0.f,0.f,0.f,0.f},{0.f,0.f,0.f,0.f},{0.f,0.f,0.f,0.f},{0.f,0.f,0.f,0.f}};

  bf16x8 ah0 = *reinterpret_cast<const bf16x8*>(ahp);
  bf16x8 ah1 = *reinterpret_cast<const bf16x8*>(ahp + 32);
  {
    const bf16x8 b0 = *reinterpret_cast<const bf16x8*>(sp);
    const bf16x8 b1 = *reinterpret_cast<const bf16x8*>(sp + 32);
    *reinterpret_cast<bf16x8*>(&Bs[0][(size_t)tid * 8]) = b0;
    *reinterpret_cast<bf16x8*>(&Bs[0][((size_t)tid + 256) * 8]) = b1;
  }
  __syncthreads();

  int cur = 0;
  #pragma unroll
  for (int kk = 0; kk < 4; kk++) {
    bf16x8 nb0 = {}, nb1 = {}, nah0 = {}, nah1 = {};
    if (kk < 3) {
      const int ko = (kk + 1) * 64;
      nb0  = *reinterpret_cast<const bf16x8*>(sp + ko);
      nb1  = *reinterpret_cast<const bf16x8*>(sp + ko + 32);
      nah0 = *reinterpret_cast<const bf16x8*>(ahp + ko);
      nah1 = *reinterpret_cast<const bf16x8*>(ahp + ko + 32);
    }
    #pragma unroll
    for (int ns = 0; ns < 4; ns++) {
      const bf16x8 bh0 = *reinterpret_cast<const bf16x8*>(&Bs[cur][(size_t)(ns * 64 + lane) * 8]);
      const bf16x8 bh1 = *reinterpret_cast<const bf16x8*>(&Bs[cur][(size_t)((ns + 4) * 64 + lane) * 8]);
      acc[ns] = __builtin_amdgcn_mfma_f32_16x16x32_bf16(ah0, bh0, acc[ns], 0, 0, 0);
      acc[ns] = __builtin_amdgcn_mfma_f32_16x16x32_bf16(ah1, bh1, acc[ns], 0, 0, 0);
    }
    if (kk < 3) {
      *reinterpret_cast<bf16x8*>(&Bs[cur ^ 1][(size_t)tid * 8]) = nb0;
      *reinterpret_cast<bf16x8*>(&Bs[cur ^ 1][((size_t)tid + 256) * 8]) = nb1;
      ah0 = nah0; ah1 = nah1;
    }
    __syncthreads();
    cur ^= 1;
  }

  if (by < 4 || by >= 8) {
    const int orow0 = (by < 4 ? by * 64 : (by - 8) * 64 + 512) + w * 16 + 4 * g;
    #pragma unroll
    for (int ns = 0; ns < 4; ns++)
      #pragma unroll
      for (int r = 0; r < 4; r++)
        Qkv[(size_t)(orow0 + r) * N_TOK + n0 + ns * 16 + lq] = f2bf(acc[ns][r]);
  } else {
    const int ok0 = (by - 4) * 64 + w * 16 + 4 * g;
    const int hh = ok0 >> 5, d0 = ok0 & 31;
    #pragma unroll
    for (int ns = 0; ns < 4; ns++) {
      ushort4 u;
      u.x = f2bf(acc[ns][0]); u.y = f2bf(acc[ns][1]);
      u.z = f2bf(acc[ns][2]); u.w = f2bf(acc[ns][3]);
      *reinterpret_cast<ushort4*>(&Kt[((size_t)hh * N_TOK + n0 + ns * 16 + lq) * HDIM + d0]) = u;
    }
  }
}

// ---------------------------------------------------------------------------
// Kernel 2: MFMA flash attention (R9-proven dual-Q, KSPLIT=4, NT=16),
// bf16 partials.
// ---------------------------------------------------------------------------
__global__ __launch_bounds__(256) void attn_mfma(
    const unsigned short* __restrict__ Qkv,
    const unsigned short* __restrict__ Kt,
    unsigned short* __restrict__ Opb,
    float* __restrict__ lpart)
{
  const int h  = blockIdx.z;
  const int ks = blockIdx.y;
  const int tid  = threadIdx.x;
  const int w    = tid >> 6;
  const int lane = tid & 63;
  const int lq   = lane & 15;
  const int g    = lane >> 4;
  const int nqa  = blockIdx.x * 128 + w * 32 + lq;
  const int nqb  = nqa + 16;

  __shared__ unsigned short KbL[2][2048];
  __shared__ unsigned short VbL[2][2048];

  bf16x8 qfa, qfb;
  {
    const unsigned short* Qh = Qkv + h * HDIM * N_TOK;
    #pragma unroll
    for (int j = 0; j < 8; j++) {
      qfa[j] = (short)Qh[(8 * g + j) * N_TOK + nqa];
      qfb[j] = (short)Qh[(8 * g + j) * N_TOK + nqb];
    }
  }

  const unsigned short* KtH = Kt + (size_t)h * N_TOK * HDIM;
  const unsigned short* VH  = Qkv + (512 + h * HDIM) * N_TOK;
  const int kbase = ks * (N_TOK / KSPLIT);       // 1024 keys per split
  const int pr = 8 * (lq >> 2) + (lq & 3);

  const int skey  = (w & 1) * 4 + (w >> 1) * 32 + pr;
  const unsigned short* ksrc = &KtH[(size_t)(kbase + skey) * HDIM + 8 * g];
  const int sdrow = (w & 1) * 16 + lq;
  const unsigned short* vsrc = &VH[(size_t)sdrow * N_TOK + kbase + (w >> 1) * 32 + 8 * g];

  {
    const bf16x8 kr = *reinterpret_cast<const bf16x8*>(ksrc);
    const bf16x8 vr = *reinterpret_cast<const bf16x8*>(vsrc);
    *reinterpret_cast<bf16x8*>(&KbL[0][tid * 8]) = kr;
    *reinterpret_cast<bf16x8*>(&VbL[0][tid * 8]) = vr;
  }
  __syncthreads();

  f32x4 o0a = {0.f,0.f,0.f,0.f}, o1a = {0.f,0.f,0.f,0.f};
  f32x4 o0b = {0.f,0.f,0.f,0.f}, o1b = {0.f,0.f,0.f,0.f};
  f32x4 laa = {0.f,0.f,0.f,0.f}, lab = {0.f,0.f,0.f,0.f};
  const f32x4 zz = {0.f,0.f,0.f,0.f};
  constexpr int NT = (N_TOK / KSPLIT) / 64;      // 16 tiles

  int cur = 0;
  #pragma unroll 2
  for (int t = 0; t < NT; ++t) {
    bf16x8 kr = {}, vr = {};
    if (t + 1 < NT) {
      kr = *reinterpret_cast<const bf16x8*>(ksrc + (size_t)(t + 1) * 64 * HDIM);
      vr = *reinterpret_cast<const bf16x8*>(vsrc + (t + 1) * 64);
    }

    const unsigned short* kb = &KbL[cur][0];
    const unsigned short* vb = &VbL[cur][0];
    const bf16x8 kf0 = *reinterpret_cast<const bf16x8*>(&kb[lane * 8]);
    const bf16x8 kf1 = *reinterpret_cast<const bf16x8*>(&kb[lane * 8 + 512]);
    const bf16x8 kf2 = *reinterpret_cast<const bf16x8*>(&kb[lane * 8 + 1024]);
    const bf16x8 kf3 = *reinterpret_cast<const bf16x8*>(&kb[lane * 8 + 1536]);

    // ---- q-frag a ----
    f32x4 s0 = __builtin_amdgcn_mfma_f32_16x16x32_bf16(kf0, qfa, zz, 0, 0, 0);
    f32x4 s1 = __builtin_amdgcn_mfma_f32_16x16x32_bf16(kf1, qfa, zz, 0, 0, 0);
    f32x4 s2 = __builtin_amdgcn_mfma_f32_16x16x32_bf16(kf2, qfa, zz, 0, 0, 0);
    f32x4 s3 = __builtin_amdgcn_mfma_f32_16x16x32_bf16(kf3, qfa, zz, 0, 0, 0);
    #pragma unroll
    for (int r = 0; r < 4; r++) {
      s0[r] = fexp2(s0[r]); s1[r] = fexp2(s1[r]);
      s2[r] = fexp2(s2[r]); s3[r] = fexp2(s3[r]);
    }
    laa += s0; laa += s1; laa += s2; laa += s3;
    const u32x4 pua_a = { cvt_pk(s0[0], s0[1]), cvt_pk(s0[2], s0[3]),
                          cvt_pk(s1[0], s1[1]), cvt_pk(s1[2], s1[3]) };
    const u32x4 pub_a = { cvt_pk(s2[0], s2[1]), cvt_pk(s2[2], s2[3]),
                          cvt_pk(s3[0], s3[1]), cvt_pk(s3[2], s3[3]) };
    const bf16x8 pfa_a = __builtin_bit_cast(bf16x8, pua_a);
    const bf16x8 pfb_a = __builtin_bit_cast(bf16x8, pub_a);

    // ---- q-frag b ----
    f32x4 t0 = __builtin_amdgcn_mfma_f32_16x16x32_bf16(kf0, qfb, zz, 0, 0, 0);
    f32x4 t1 = __builtin_amdgcn_mfma_f32_16x16x32_bf16(kf1, qfb, zz, 0, 0, 0);
    f32x4 t2 = __builtin_amdgcn_mfma_f32_16x16x32_bf16(kf2, qfb, zz, 0, 0, 0);
    f32x4 t3 = __builtin_amdgcn_mfma_f32_16x16x32_bf16(kf3, qfb, zz, 0, 0, 0);
    #pragma unroll
    for (int r = 0; r < 4; r++) {
      t0[r] = fexp2(t0[r]); t1[r] = fexp2(t1[r]);
      t2[r] = fexp2(t2[r]); t3[r] = fexp2(t3[r]);
    }
    lab += t0; lab += t1; lab += t2; lab += t3;
    const u32x4 pua_b = { cvt_pk(t0[0], t0[1]), cvt_pk(t0[2], t0[3]),
                          cvt_pk(t1[0], t1[1]), cvt_pk(t1[2], t1[3]) };
    const u32x4 pub_b = { cvt_pk(t2[0], t2[1]), cvt_pk(t2[2], t2[3]),
                          cvt_pk(t3[0], t3[1]), cvt_pk(t3[2], t3[3]) };
    const bf16x8 pfa_b = __builtin_bit_cast(bf16x8, pua_b);
    const bf16x8 pfb_b = __builtin_bit_cast(bf16x8, pub_b);

    const bf16x8 vf0a = *reinterpret_cast<const bf16x8*>(&vb[lane * 8]);
    const bf16x8 vf1a = *reinterpret_cast<const bf16x8*>(&vb[lane * 8 + 512]);
    const bf16x8 vf0b = *reinterpret_cast<const bf16x8*>(&vb[lane * 8 + 1024]);
    const bf16x8 vf1b = *reinterpret_cast<const bf16x8*>(&vb[lane * 8 + 1536]);

    o0a = __builtin_amdgcn_mfma_f32_16x16x32_bf16(vf0a, pfa_a, o0a, 0, 0, 0);
    o0a = __builtin_amdgcn_mfma_f32_16x16x32_bf16(vf0b, pfb_a, o0a, 0, 0, 0);
    o1a = __builtin_amdgcn_mfma_f32_16x16x32_bf16(vf1a, pfa_a, o1a, 0, 0, 0);
    o1a = __builtin_amdgcn_mfma_f32_16x16x32_bf16(vf1b, pfb_a, o1a, 0, 0, 0);
    o0b = __builtin_amdgcn_mfma_f32_16x16x32_bf16(vf0a, pfa_b, o0b, 0, 0, 0);
    o0b = __builtin_amdgcn_mfma_f32_16x16x32_bf16(vf0b, pfb_b, o0b, 0, 0, 0);
    o1b = __builtin_amdgcn_mfma_f32_16x16x32_bf16(vf1a, pfa_b, o1b, 0, 0, 0);
    o1b = __builtin_amdgcn_mfma_f32_16x16x32_bf16(vf1b, pfb_b, o1b, 0, 0, 0);

    if (t + 1 < NT) {
      *reinterpret_cast<bf16x8*>(&KbL[cur ^ 1][tid * 8]) = kr;
      *reinterpret_cast<bf16x8*>(&VbL[cur ^ 1][tid * 8]) = vr;
    }
    __syncthreads();
    cur ^= 1;
  }

  float lsa = (laa[0] + laa[1]) + (laa[2] + laa[3]);
  lsa += __shfl_xor(lsa, 16);
  lsa += __shfl_xor(lsa, 32);
  float lsb = (lab[0] + lab[1]) + (lab[2] + lab[3]);
  lsb += __shfl_xor(lsb, 16);
  lsb += __shfl_xor(lsb, 32);

  const int ob = (ks * HEADS + h) * HDIM;
  #pragma unroll
  for (int r = 0; r < 4; r++) {
    Opb[(size_t)(ob + 4 * g + r) * N_TOK + nqa]      = f2bf(o0a[r]);
    Opb[(size_t)(ob + 16 + 4 * g + r) * N_TOK + nqa] = f2bf(o1a[r]);
    Opb[(size_t)(ob + 4 * g + r) * N_TOK + nqb]      = f2bf(o0b[r]);
    Opb[(size_t)(ob + 16 + 4 * g + r) * N_TOK + nqb] = f2bf(o1b[r]);
  }
  if (g == 0) {
    lpart[(ks * HEADS + h) * N_TOK + nqa] = lsa;
    lpart[(ks * HEADS + h) * N_TOK + nqb] = lsb;
  }
}

// ---------------------------------------------------------------------------
// Kernel 3: combine (sum bf16 partials, /L) + transpose -> Ob bf16 [n][o]
// ---------------------------------------------------------------------------
__global__ __launch_bounds__(256) void combsplit(
    const unsigned short* __restrict__ Opb, const float* __restrict__ lpart,
    unsigned short* __restrict__ Ob)
{
  __shared__ float T[64][69];
  __shared__ float Linv[2][64];
  const int o0 = blockIdx.y * 64, n0 = blockIdx.x * 64;
  const int t = threadIdx.x;
  if (t < 128) {
    const int hl = t >> 6, nl = t & 63;
    const int hh = (o0 >> 5) + hl;
    float L = 0.f;
    #pragma unroll
    for (int ks = 0; ks < KSPLIT; ks++)
      L += lpart[(ks * HEADS + hh) * N_TOK + n0 + nl];
    Linv[hl][nl] = 1.f / L;
  }
  __syncthreads();
  {
    const int cl = t >> 2, ng = (t & 3) * 16;
    const int hrow = cl >> 5;
    #pragma unroll
    for (int jj = 0; jj < 4; jj++) {
      float a0 = 0.f, a1 = 0.f, a2 = 0.f, a3 = 0.f;
      #pragma unroll
      for (int ks = 0; ks < KSPLIT; ks++) {
        const ushort4 u = *reinterpret_cast<const ushort4*>(
            &Opb[(size_t)ks * C_DIM * N_TOK + (size_t)(o0 + cl) * N_TOK + n0 + ng + jj * 4]);
        a0 += bf2f(u.x); a1 += bf2f(u.y); a2 += bf2f(u.z); a3 += bf2f(u.w);
      }
      T[cl][ng + jj * 4 + 0] = a0 * Linv[hrow][ng + jj * 4 + 0];
      T[cl][ng + jj * 4 + 1] = a1 * Linv[hrow][ng + jj * 4 + 1];
      T[cl][ng + jj * 4 + 2] = a2 * Linv[hrow][ng + jj * 4 + 2];
      T[cl][ng + jj * 4 + 3] = a3 * Linv[hrow][ng + jj * 4 + 3];
    }
  }
  __syncthreads();
  {
    const int nl = t >> 2, cg = (t & 3) * 16;
    u16x8 h0, h1;
    #pragma unroll
    for (int j = 0; j < 8; j++) h0[j] = f2bf(T[cg + j][nl]);
    #pragma unroll
    for (int j = 0; j < 8; j++) h1[j] = f2bf(T[cg + 8 + j][nl]);
    const size_t base = (size_t)(n0 + nl) * C_DIM + o0 + cg;
    *reinterpret_cast<u16x8*>(&Ob[base])     = h0;
    *reinterpret_cast<u16x8*>(&Ob[base + 8]) = h1;
  }
}

// ---------------------------------------------------------------------------
// Kernel 4: out projection (single bf16, 32c x 64n tiles, 512 blocks)
// + fused depthwise 3x3 conv epilogue (8 outputs/thread).
// ---------------------------------------------------------------------------
__global__ __launch_bounds__(256) void out_mfma(
    const unsigned short* __restrict__ Wb,
    const unsigned short* __restrict__ Ob,
    const float* __restrict__ x, const float* __restrict__ wl,
    float* __restrict__ out)
{
  const int n0 = blockIdx.x * 64;
  const int c0 = blockIdx.y * 32;
  const int tid = threadIdx.x;
  const int w = tid >> 6, lane = tid & 63, lq = lane & 15, g = lane >> 4;
  const int wc = w & 1, wn = w >> 1;         // c-half, n-half
  const int cw = c0 + wc * 16;

  __shared__ unsigned short Bs[2][4096];     // 64n x 64k

  const int lane_ = tid & 63, ns_ = tid >> 6;
  const unsigned short* sp = Ob + (size_t)(n0 + ns_ * 16 + (lane_ & 15)) * C_DIM + 8 * (lane_ >> 4);
  const unsigned short* ahp = &Wb[(size_t)(768 + cw + lq) * C_DIM + 8 * g];

  f32x4 acc[2] = {{0.f,0.f,0.f,0.f},{0.f,0.f,0.f,0.f}};

  bf16x8 ah0 = *reinterpret_cast<const bf16x8*>(ahp);
  bf16x8 ah1 = *reinterpret_cast<const bf16x8*>(ahp + 32);
  {
    const bf16x8 b0 = *reinterpret_cast<const bf16x8*>(sp);
    const bf16x8 b1 = *reinterpret_cast<const bf16x8*>(sp + 32);
    *reinterpret_cast<bf16x8*>(&Bs[0][(size_t)tid * 8]) = b0;
    *reinterpret_cast<bf16x8*>(&Bs[0][((size_t)tid + 256) * 8]) = b1;
  }
  __syncthreads();

  int cur = 0;
  #pragma unroll
  for (int kk = 0; kk < 4; kk++) {
    bf16x8 nb0 = {}, nb1 = {}, nah0 = {}, nah1 = {};
    if (kk < 3) {
      const int ko = (kk + 1) * 64;
      nb0  = *reinterpret_cast<const bf16x8*>(sp + ko);
      nb1  = *reinterpret_cast<const bf16x8*>(sp + ko + 32);
      nah0 = *reinterpret_cast<const bf16x8*>(ahp + ko);
      nah1 = *reinterpret_cast<const bf16x8*>(ahp + ko + 32);
    }
    #pragma unroll
    for (int ns = 0; ns < 2; ns++) {
      const int nsg = wn * 2 + ns;
      const bf16x8 bh0 = *reinterpret_cast<const bf16x8*>(&Bs[cur][(size_t)(nsg * 64 + lane) * 8]);
      const bf16x8 bh1 = *reinterpret_cast<const bf16x8*>(&Bs[cur][(size_t)((nsg + 4) * 64 + lane) * 8]);
      acc[ns] = __builtin_amdgcn_mfma_f32_16x16x32_bf16(ah0, bh0, acc[ns], 0, 0, 0);
      acc[ns] = __builtin_amdgcn_mfma_f32_16x16x32_bf16(ah1, bh1, acc[ns], 0, 0, 0);
    }
    if (kk < 3) {
      *reinterpret_cast<bf16x8*>(&Bs[cur ^ 1][(size_t)tid * 8]) = nb0;
      *reinterpret_cast<bf16x8*>(&Bs[cur ^ 1][((size_t)tid + 256) * 8]) = nb1;
      ah0 = nah0; ah1 = nah1;
    }
    __syncthreads();
    cur ^= 1;
  }

  // fused depthwise conv epilogue: this block's n-range is image row yy = bx
  const int yy = blockIdx.x;
  #pragma unroll
  for (int ns = 0; ns < 2; ns++) {
    #pragma unroll
    for (int r = 0; r < 4; r++) {
      const int c = cw + 4 * g + r;
      const int n = n0 + wn * 32 + ns * 16 + lq;
      const int xx = n & 63;
      const float* xc  = x + (size_t)c * 4096;
      const float* wl9 = wl + (size_t)c * 9;
      float cv = 0.f;
      #pragma unroll
      for (int dy = 0; dy < 3; dy++) {
        const int y2 = yy + dy - 1;
        if (y2 < 0 || y2 > 63) continue;
        #pragma unroll
        for (int dx = 0; dx < 3; dx++) {
          const int x2 = xx + dx - 1;
          if (x2 < 0 || x2 > 63) continue;
          cv += wl9[dy * 3 + dx] * xc[y2 * 64 + x2];
        }
      }
      out[(size_t)c * N_TOK + n] = cv + acc[ns][r];
    }
  }
}

// ---------------------------------------------------------------------------
extern "C" void kernel_launch(void* const* d_in, const int* in_sizes, int n_in,
                              void* d_out, int out_size, void* d_ws, size_t ws_size,
                              hipStream_t stream) {
  const float* x  = (const float*)d_in[0];
  const float* wq = (const float*)d_in[1];
  const float* wk = (const float*)d_in[2];
  const float* wv = (const float*)d_in[3];
  const float* wo = (const float*)d_in[4];
  const float* wl = (const float*)d_in[5];
  float* out = (float*)d_out;

  unsigned short* Opb = (unsigned short*)d_ws;                  // 4*256*4096 us
  float* lpart = (float*)(Opb + (size_t)KSPLIT * C_DIM * N_TOK);// 4*8*4096 f
  unsigned short* Qkv = (unsigned short*)(lpart + KSPLIT * HEADS * N_TOK);
  unsigned short* Kt  = Qkv + 768 * N_TOK;                      // 8*4096*32
  unsigned short* Wb  = Kt + (size_t)HEADS * N_TOK * HDIM;      // 1024*256
  unsigned short* Xb  = Wb + 1024 * C_DIM;                      // 4096*256
  unsigned short* Ob  = Xb + (size_t)N_TOK * C_DIM;             // 4096*256
  // total ~23 MB

  prep<<<512, 256, 0, stream>>>(wq, wk, wv, wo, x, Wb, Xb);
  qkv_mfma<<<dim3(64, 12), 256, 0, stream>>>(Wb, Xb, Qkv, Kt);
  attn_mfma<<<dim3(32, KSPLIT, HEADS), 256, 0, stream>>>(Qkv, Kt, Opb, lpart);
  combsplit<<<dim3(64, 4), 256, 0, stream>>>(Opb, lpart, Ob);
  out_mfma<<<dim3(64, 8), 256, 0, stream>>>(Wb, Ob, x, wl, out);
}